// Round 8
// baseline (431.746 us; speedup 1.0000x reference)
//
#include <hip/hip_runtime.h>

typedef int      iv4 __attribute__((ext_vector_type(4)));
typedef unsigned uv4 __attribute__((ext_vector_type(4)));

// ==== v8: chunk-local LDS sort (+region sidecar) + flat pipelined sweep ====
#define NREGS   128               // x regions, 256 KB each at n_x = 2^23
#define RSH     16                // region shift: ptr >> 16
#define BLK1    512
#define EPT1    16
#define CHUNK1  (BLK1 * EPT1)     // 8192 edges per pass-1 chunk
#define CPB     16                // chunks per consume block (= waves in pass 2)
#define BLK2    1024
#define CAP     38400             // LDS segment-accumulator capacity (floats)

// ---- Pass 1: sort each 8192-edge chunk by region, write contiguously ----
__global__ __launch_bounds__(BLK1) void sort_chunks_kernel(
    const float* __restrict__ x,     // only for the (rare) sentinel path
    const int*   __restrict__ ptrs,
    const int*   __restrict__ csr,
    float*       __restrict__ out,
    unsigned*       __restrict__ wse,  // [n_edges] packed entries, chunk-contiguous
    unsigned char*  __restrict__ wsr,  // [n_edges] region byte per slot (or null)
    int*            __restrict__ wsb,  // [n_chunks * (NREGS+1)] per-chunk bounds
    long long eb)                      // edges per consume block = CPB*CHUNK1
{
    __shared__ int      hist[NREGS];      // counts -> scatter cursors
    __shared__ int      bounds[NREGS + 1];
    __shared__ unsigned packed[CHUNK1];   // 32 KB

    const int c = blockIdx.x, tid = threadIdx.x;
    const long long base = (long long)c * CHUNK1;
    const int cb = (int)(base / eb);                  // owning consume block
    const int seg_base = csr[(long long)cb * eb];

    if (tid < NREGS) hist[tid] = 0;
    __syncthreads();

    // coalesced index loads into registers
    int ps[EPT1], cs[EPT1];
    const iv4* p4 = reinterpret_cast<const iv4*>(ptrs + base);
    const iv4* s4 = reinterpret_cast<const iv4*>(csr + base);
    #pragma unroll
    for (int q = 0; q < EPT1 / 4; ++q) {
        iv4 p = __builtin_nontemporal_load(p4 + q * BLK1 + tid);
        ps[q*4+0] = p[0]; ps[q*4+1] = p[1]; ps[q*4+2] = p[2]; ps[q*4+3] = p[3];
    }
    #pragma unroll
    for (int q = 0; q < EPT1 / 4; ++q) {
        iv4 s = __builtin_nontemporal_load(s4 + q * BLK1 + tid);
        cs[q*4+0] = s[0]; cs[q*4+1] = s[1]; cs[q*4+2] = s[2]; cs[q*4+3] = s[3];
    }

    // histogram
    #pragma unroll
    for (int i = 0; i < EPT1; ++i) atomicAdd(&hist[ps[i] >> RSH], 1);
    __syncthreads();
    if (tid == 0) {
        int acc = 0;
        #pragma unroll
        for (int r = 0; r < NREGS; ++r) { bounds[r] = acc; acc += hist[r]; }
        bounds[NREGS] = acc;                           // == CHUNK1
    }
    __syncthreads();
    if (tid < NREGS) hist[tid] = bounds[tid];          // cursors
    __syncthreads();

    // rank + scatter into LDS (unstable ranking fine: consumer accumulates
    // order-independently via LDS atomics)
    #pragma unroll
    for (int i = 0; i < EPT1; ++i) {
        int pp = ps[i], ss = cs[i];
        int r  = pp >> RSH;
        int sl = ss - seg_base;
        unsigned pk;
        if (sl >= 0xFFFF) {                            // pathological: direct add
            atomicAdd(out + ss, x[pp]);
            pk = (((unsigned)pp & 0xFFFFu) << 16) | 0xFFFFu;   // NOP sentinel
        } else {
            pk = (((unsigned)pp & 0xFFFFu) << 16) | (unsigned)sl;
        }
        int pos = atomicAdd(&hist[r], 1);
        packed[pos] = pk;
    }
    __syncthreads();

    // contiguous coalesced write-out of the sorted chunk (16 KB)
    {
        const uv4* pl = reinterpret_cast<const uv4*>(packed);
        uv4* w4 = reinterpret_cast<uv4*>(wse + base);
        for (int i = tid; i < CHUNK1 / 4; i += BLK1)
            __builtin_nontemporal_store(pl[i], w4 + i);
    }
    // region sidecar: 1 byte per slot; thread owns slots [tid*16, tid*16+16)
    if (wsr) {
        const int s0 = tid * EPT1;
        int lo = 0, hi = NREGS;          // invariant: bounds[lo] <= s0 < bounds[hi]
        while (hi - lo > 1) {
            int mid = (lo + hi) >> 1;
            if (bounds[mid] <= s0) lo = mid; else hi = mid;
        }
        int r = lo;
        union { unsigned char b[16]; uv4 v; } rbuf;
        #pragma unroll
        for (int i = 0; i < EPT1; ++i) {
            while (bounds[r + 1] <= s0 + i) ++r;
            rbuf.b[i] = (unsigned char)r;
        }
        __builtin_nontemporal_store(rbuf.v,
            reinterpret_cast<uv4*>(wsr + base + s0));
    }
    for (int i = tid; i <= NREGS; i += BLK1)
        wsb[(size_t)c * (NREGS + 1) + i] = bounds[i];
}

// ---- Pass 2 (v8): flat region-major sweep, 8-deep pipelined gathers ----
__global__ __launch_bounds__(BLK2) void consume_flat_kernel(
    const float*         __restrict__ x,
    const int*           __restrict__ csr,
    float*               __restrict__ out,
    const unsigned*      __restrict__ wse,
    const unsigned char* __restrict__ wsr,
    long long eb)
{
    __shared__ float accum[CAP];                 // 150 KB

    const int c = blockIdx.x, tid = threadIdx.x;
    const int w = tid >> 6, lane = tid & 63;
    const long long base = (long long)c * eb;

    for (int i = tid; i < CAP; i += BLK2) accum[i] = 0.f;
    const int seg_base = csr[base];
    const int seg_last = csr[base + eb - 1];
    __syncthreads();

    // Wave w walks its 8192-entry chunk linearly; entries are region-sorted,
    // so this IS the region-major order (same phase-coherent locality as the
    // region loop) but with a static trip count and fully independent loads.
    const long long cbase = base + (long long)w * CHUNK1;
    const uv4*      pk4 = reinterpret_cast<const uv4*>(wse + cbase);
    const unsigned* r4  = reinterpret_cast<const unsigned*>(wsr + cbase);

    for (int k = 0; k < CHUNK1 / (64 * 8); ++k) {      // 16 iterations
        const int e = k * 512 + lane * 8;              // entry offset in chunk
        uv4 a = __builtin_nontemporal_load(pk4 + (e >> 2));
        uv4 b = __builtin_nontemporal_load(pk4 + (e >> 2) + 1);
        unsigned ra = __builtin_nontemporal_load(r4 + (e >> 2));
        unsigned rb = __builtin_nontemporal_load(r4 + (e >> 2) + 1);

        unsigned pk[8] = { a[0], a[1], a[2], a[3], b[0], b[1], b[2], b[3] };
        int rg[8];
        #pragma unroll
        for (int j = 0; j < 4; ++j) rg[j]     = (int)((ra >> (8 * j)) & 0xFFu);
        #pragma unroll
        for (int j = 0; j < 4; ++j) rg[4 + j] = (int)((rb >> (8 * j)) & 0xFFu);

        // 8 independent gathers in flight
        float v[8];
        #pragma unroll
        for (int j = 0; j < 8; ++j)
            v[j] = x[(rg[j] << RSH) | (int)(pk[j] >> 16)];

        // then the LDS accumulation
        #pragma unroll
        for (int j = 0; j < 8; ++j) {
            int sl = (int)(pk[j] & 0xFFFFu);
            if (sl == 0xFFFF) continue;                // handled in pass 1
            if (sl < CAP) atomicAdd(&accum[sl], v[j]);
            else          atomicAdd(out + seg_base + sl, v[j]);   // rare overflow
        }
    }
    __syncthreads();

    // Flush: interior segments exclusive (csr sorted) -> plain coalesced
    // stores; the two block-boundary segments may be shared -> atomicAdd.
    const int range = seg_last - seg_base + 1;
    const int hi = range < CAP ? range : CAP;
    for (int i = tid; i < hi; i += BLK2) {
        float v = accum[i];
        if (i == 0 || i == range - 1) {
            if (v != 0.f) atomicAdd(out + seg_base + i, v);
        } else {
            out[seg_base + i] = v;
        }
    }
}

// ---- Pass 2 (v7 fallback, ws too small for sidecar): per-region slices ----
__global__ __launch_bounds__(BLK2) void consume_kernel(
    const float*    __restrict__ x,
    const int*      __restrict__ csr,
    float*          __restrict__ out,
    const unsigned* __restrict__ wse,
    const int*      __restrict__ wsb,
    long long eb)
{
    __shared__ float accum[CAP];
    __shared__ int   cbnd[CPB][NREGS + 1];

    const int c = blockIdx.x, tid = threadIdx.x;
    const int w = tid >> 6, lane = tid & 63;
    const long long base = (long long)c * eb;

    for (int i = tid; i < CAP; i += BLK2) accum[i] = 0.f;
    {
        const int* src = wsb + (size_t)c * CPB * (NREGS + 1);
        for (int i = tid; i < CPB * (NREGS + 1); i += BLK2)
            (&cbnd[0][0])[i] = src[i];
    }
    const int seg_base = csr[base];
    const int seg_last = csr[base + eb - 1];
    __syncthreads();

    const long long chunk_base = base + (long long)w * CHUNK1;
    for (int r = 0; r < NREGS; ++r) {
        const int lo = cbnd[w][r], hi = cbnd[w][r + 1];
        const int rb = r << RSH;
        for (int i = lo + lane; i < hi; i += 64) {
            unsigned pk = __builtin_nontemporal_load(wse + chunk_base + i);
            float val = x[rb | (int)(pk >> 16)];
            int   sl  = (int)(pk & 0xFFFFu);
            if (sl == 0xFFFF) continue;
            if (sl < CAP) atomicAdd(&accum[sl], val);
            else          atomicAdd(out + seg_base + sl, val);
        }
    }
    __syncthreads();

    const int range = seg_last - seg_base + 1;
    const int hi = range < CAP ? range : CAP;
    for (int i = tid; i < hi; i += BLK2) {
        float v = accum[i];
        if (i == 0 || i == range - 1) {
            if (v != 0.f) atomicAdd(out + seg_base + i, v);
        } else {
            out[seg_base + i] = v;
        }
    }
}

// =================== round-5 fallback (generic sizes) ===================
#define EPT   16
#define BLK   256
#define CHUNK (BLK * EPT)
#define NREG  16
#define SW(s) ((s) ^ (((s) >> 4) & 0xF))

__global__ __launch_bounds__(BLK, 4) void seg_gather_sort_kernel(
    const float* __restrict__ x,
    const int*   __restrict__ ptrs,
    const int*   __restrict__ csr,
    float*       __restrict__ out,
    int n_edges, int rshift, int n_chunks)
{
    __shared__ int      hist[NREG];
    __shared__ int      bounds[NREG + 1];
    __shared__ unsigned packed[CHUNK];
    __shared__ float    vlds[CHUNK];

    const int tid = threadIdx.x;
    const unsigned lmask = (1u << rshift) - 1u;

    for (int c = blockIdx.x; c < n_chunks; c += gridDim.x) {
        const long long base_e = (long long)c * CHUNK;
        if (base_e + CHUNK <= n_edges) {
            const long long e0 = base_e + (long long)tid * EPT;
            const iv4* p4 = reinterpret_cast<const iv4*>(ptrs + e0);
            const iv4* c4 = reinterpret_cast<const iv4*>(csr + e0);
            int ps[EPT], cs[EPT];
            #pragma unroll
            for (int q = 0; q < EPT / 4; ++q) {
                iv4 p = __builtin_nontemporal_load(p4 + q);
                ps[q*4+0] = p[0]; ps[q*4+1] = p[1]; ps[q*4+2] = p[2]; ps[q*4+3] = p[3];
            }
            #pragma unroll
            for (int q = 0; q < EPT / 4; ++q) {
                iv4 cc = __builtin_nontemporal_load(c4 + q);
                cs[q*4+0] = cc[0]; cs[q*4+1] = cc[1]; cs[q*4+2] = cc[2]; cs[q*4+3] = cc[3];
            }
            if (tid < NREG) hist[tid] = 0;
            __syncthreads();
            #pragma unroll
            for (int i = 0; i < EPT; ++i) atomicAdd(&hist[ps[i] >> rshift], 1);
            __syncthreads();
            if (tid == 0) {
                int acc = 0; bounds[0] = 0;
                #pragma unroll
                for (int r = 0; r < NREG; ++r) { acc += hist[r]; bounds[r+1] = acc; }
                #pragma unroll
                for (int r = 0; r < NREG; ++r) hist[r] = bounds[r];
            }
            __syncthreads();
            #pragma unroll
            for (int i = 0; i < EPT; ++i) {
                int r   = ps[i] >> rshift;
                int pos = atomicAdd(&hist[r], 1);
                packed[pos] = (((unsigned)ps[i] & lmask) << 12) | (unsigned)(tid*EPT+i);
            }
            __syncthreads();
            {
                int r = 0;
                #pragma unroll
                for (int k = 0; k < EPT; ++k) {
                    int e = k * BLK + tid;
                    while (e >= bounds[r + 1]) ++r;
                    unsigned pk = packed[e];
                    int ptr  = (r << rshift) | (int)(pk >> 12);
                    int slot = (int)(pk & 0xFFFu);
                    vlds[SW(slot)] = x[ptr];
                }
            }
            __syncthreads();
            float v[EPT];
            #pragma unroll
            for (int i = 0; i < EPT; ++i) v[i] = vlds[SW(tid * EPT + i)];
            int cur = cs[0]; float sum = 0.f; bool first = true;
            #pragma unroll
            for (int i = 0; i < EPT; ++i) {
                int seg = cs[i];
                if (seg != cur) {
                    if (first) { atomicAdd(out + cur, sum); first = false; }
                    else       { out[cur] = sum; }
                    cur = seg; sum = 0.f;
                }
                sum += v[i];
            }
            atomicAdd(out + cur, sum);
            __syncthreads();
        } else {
            long long e0 = base_e + (long long)tid * EPT;
            if (e0 < n_edges) {
                long long eend = e0 + EPT; if (eend > n_edges) eend = n_edges;
                int cur = csr[e0]; float sum = 0.f; bool first = true;
                for (long long e = e0; e < eend; ++e) {
                    int seg = csr[e];
                    if (seg != cur) {
                        if (first) { atomicAdd(out + cur, sum); first = false; }
                        else       { out[cur] = sum; }
                        cur = seg; sum = 0.f;
                    }
                    sum += x[ptrs[e]];
                }
                atomicAdd(out + cur, sum);
            }
        }
    }
}

extern "C" void kernel_launch(void* const* d_in, const int* in_sizes, int n_in,
                              void* d_out, int out_size, void* d_ws, size_t ws_size,
                              hipStream_t stream) {
    const float* x    = (const float*)d_in[0];
    const int*   ptrs = (const int*)d_in[1];
    const int*   csr  = (const int*)d_in[2];
    float*       out  = (float*)d_out;

    const int n_x     = in_sizes[0];
    const int n_edges = in_sizes[2];

    // Zero base for atomics + empty segments (d_out poisoned by harness).
    (void)hipMemsetAsync(out, 0, (size_t)out_size * sizeof(float), stream);

    const long long eb = (long long)CHUNK1 * CPB;     // 131072
    const int n_chunks1 = (int)(n_edges / CHUNK1);
    const size_t bounds_bytes = (size_t)n_chunks1 * (NREGS + 1) * 4;
    const size_t ws_need_v7 = (size_t)n_edges * 4 + bounds_bytes;
    const size_t ws_need_v8 = (size_t)n_edges * 5 + bounds_bytes;
    const bool shape_ok = (n_edges % eb == 0) && (n_x <= (NREGS << RSH));

    if (shape_ok && ws_size >= ws_need_v8) {
        // layout: [wse: n_edges u32][wsr: n_edges u8][wsb: bounds]
        unsigned*      wse = (unsigned*)d_ws;
        unsigned char* wsr = (unsigned char*)d_ws + (size_t)n_edges * 4;
        int*           wsb = (int*)(void*)((char*)d_ws + (size_t)n_edges * 5);
        const int g2 = (int)(n_edges / eb);
        sort_chunks_kernel<<<n_chunks1, BLK1, 0, stream>>>(
            x, ptrs, csr, out, wse, wsr, wsb, eb);
        consume_flat_kernel<<<g2, BLK2, 0, stream>>>(
            x, csr, out, wse, wsr, eb);
    } else if (shape_ok && ws_size >= ws_need_v7) {
        unsigned* wse = (unsigned*)d_ws;
        int*      wsb = (int*)d_ws + n_edges;
        const int g2 = (int)(n_edges / eb);
        sort_chunks_kernel<<<n_chunks1, BLK1, 0, stream>>>(
            x, ptrs, csr, out, wse, (unsigned char*)nullptr, wsb, eb);
        consume_kernel<<<g2, BLK2, 0, stream>>>(
            x, csr, out, wse, wsb, eb);
    } else {
        int rshift = 0;
        while ((1LL << rshift) < (n_x + NREG - 1) / NREG) ++rshift;
        const int n_chunks = (int)(((long long)n_edges + CHUNK - 1) / CHUNK);
        int grid = 1024; if (grid > n_chunks) grid = n_chunks;
        seg_gather_sort_kernel<<<grid, BLK, 0, stream>>>(
            x, ptrs, csr, out, n_edges, rshift, n_chunks);
    }
}